// Round 10
// baseline (341.444 us; speedup 1.0000x reference)
//
#include <hip/hip_runtime.h>

#define NSEQ  9216
#define CDIM  192
#define KTILE 64
#define LOG2E 1.44269504088896f

typedef _Float16 h8_t  __attribute__((ext_vector_type(8)));
typedef _Float16 h4_t  __attribute__((ext_vector_type(4)));
typedef _Float16 h2_t  __attribute__((ext_vector_type(2)));
typedef float    f4_t  __attribute__((ext_vector_type(4)));
typedef float    f16v  __attribute__((ext_vector_type(16)));

// ---------------------------------------------------------------------------
// Kernel 0: Wq/Wk/Wv fp32 -> f16 Wh[3][192][192].  Wq pre-scaled by log2e so
// flash softmax runs in the exp2 domain.
// ---------------------------------------------------------------------------
__global__ __launch_bounds__(256) void wconv_kernel(
    const float* __restrict__ Wq, const float* __restrict__ Wk,
    const float* __restrict__ Wv, _Float16* __restrict__ Wh)
{
    int i = blockIdx.x * 256 + threadIdx.x;     // f4 index, 3*9216 total
    if (i >= 3 * 9216) return;
    const float* src = (i < 9216) ? Wq : (i < 18432 ? Wk : Wv);
    float s = (i < 9216) ? LOG2E : 1.f;
    int r = i % 9216;
    f4_t w = ((const f4_t*)src)[r];
    h4_t h = {(_Float16)(w[0]*s), (_Float16)(w[1]*s),
              (_Float16)(w[2]*s), (_Float16)(w[3]*s)};
    ((h4_t*)Wh)[i] = h;
}

// ---------------------------------------------------------------------------
// Kernel 1: QKV projection via 32x32x16 MFMA.
//   One wave per (mat, channel-half, 32-seq chunk): 3456 waves (13.5/CU).
//   K is written in FRAGMENT-ORDERED layout KF[tile32][t][hi_f][key] (16B
//   chunks) so flash can load S^T A-fragments as single coalesced
//   global_load_dwordx4 (base + lane*16B) — no LDS staging for K at all.
// ---------------------------------------------------------------------------
__global__ __launch_bounds__(256) void proj_kernel(
    const float* __restrict__ x, const _Float16* __restrict__ Wh,
    const float* __restrict__ bq, const float* __restrict__ bk,
    const float* __restrict__ bv,
    _Float16* __restrict__ QT, _Float16* __restrict__ KF, _Float16* __restrict__ Vg)
{
    const int tid  = threadIdx.x;
    const int lane = tid & 63, wave = tid >> 6;
    const int L31  = lane & 31, hi = lane >> 5;
    const int idx  = blockIdx.x * 4 + wave;      // 0..3455
    const int mat  = idx / 1152;
    const int rem  = idx % 1152;
    const int half = rem / 576;
    const int rem2 = rem % 576;
    const int b    = rem2 / 288;
    const int n0   = (rem2 % 288) * 32;
    const int n    = n0 + L31;

    h8_t bf[12];
    #pragma unroll
    for (int t = 0; t < 12; t++) {
        h8_t h;
        #pragma unroll
        for (int j = 0; j < 8; j++)
            h[j] = (_Float16)x[(size_t)(b * CDIM + t * 16 + hi * 8 + j) * NSEQ + n];
        bf[t] = h;
    }

    const _Float16* W = Wh + mat * CDIM * CDIM + half * 96 * CDIM;
    const float* bias = ((mat == 0) ? bq : (mat == 1 ? bk : bv)) + half * 96;
    const float bscale = (mat == 0) ? LOG2E : 1.f;

    f16v acc[3];
    #pragma unroll
    for (int s = 0; s < 3; s++)
        #pragma unroll
        for (int r = 0; r < 16; r++) acc[s][r] = 0.f;

    #pragma unroll
    for (int t = 0; t < 12; t++) {
        #pragma unroll
        for (int s = 0; s < 3; s++) {
            h8_t a = *(const h8_t*)(W + (s * 32 + L31) * CDIM + t * 16 + hi * 8);
            acc[s] = __builtin_amdgcn_mfma_f32_32x32x16_f16(a, bf[t], acc[s], 0, 0, 0);
        }
    }

    if (mat == 0) {
        _Float16* dst = QT + ((size_t)b * NSEQ + n) * CDIM + half * 96;
        #pragma unroll
        for (int s = 0; s < 3; s++) {
            #pragma unroll
            for (int g = 0; g < 4; g++) {
                f4_t bb = *(const f4_t*)&bias[s * 32 + 8 * g + 4 * hi];
                h4_t h = {(_Float16)(acc[s][4*g+0] + bb[0] * bscale),
                          (_Float16)(acc[s][4*g+1] + bb[1] * bscale),
                          (_Float16)(acc[s][4*g+2] + bb[2] * bscale),
                          (_Float16)(acc[s][4*g+3] + bb[3] * bscale)};
                *(h4_t*)(dst + s * 32 + 8 * g + 4 * hi) = h;
            }
        }
    } else if (mat == 1) {
        // fragment-ordered K: chunk(t, hi_f) of key L31; channel o -> t=o>>4,
        // hi_f=(o>>3)&1, off=o&7.  o = half*96 + s*32 + 8g + 4hi + rl.
        _Float16* kf = KF + (size_t)b * (288 * 6144) + (size_t)(n0 >> 5) * 6144;
        #pragma unroll
        for (int s = 0; s < 3; s++) {
            #pragma unroll
            for (int g = 0; g < 4; g++) {
                f4_t bb = *(const f4_t*)&bias[s * 32 + 8 * g + 4 * hi];
                h4_t h = {(_Float16)(acc[s][4*g+0] + bb[0]),
                          (_Float16)(acc[s][4*g+1] + bb[1]),
                          (_Float16)(acc[s][4*g+2] + bb[2]),
                          (_Float16)(acc[s][4*g+3] + bb[3])};
                int t   = half * 6 + 2 * s + (g >> 1);
                int hif = g & 1;
                *(h4_t*)(kf + (t * 2 + hif) * 256 + L31 * 8 + 4 * hi) = h;
            }
        }
    } else {
        #pragma unroll
        for (int s = 0; s < 3; s++) {
            #pragma unroll
            for (int g = 0; g < 4; g++) {
                f4_t bb = *(const f4_t*)&bias[s * 32 + 8 * g + 4 * hi];
                #pragma unroll
                for (int r = 0; r < 4; r++) {
                    int o = half * 96 + s * 32 + 8 * g + 4 * hi + r;
                    Vg[((size_t)b * CDIM + o) * NSEQ + n] =
                        (_Float16)(acc[s][4*g+r] + bb[r]);
                }
            }
        }
    }
}

// ---------------------------------------------------------------------------
// Kernel 2: flash attention.
//   K A-frags: single coalesced global_load_dwordx4 from fragment-ordered KF
//   (L1-hot: 4 waves/block reuse; L2-hot across blocks).  Loads issue before
//   the staging barriers (~500 cyc distance) + 2-step rolling window.
//   V staged in LDS (R7's proven two-barrier pattern); P via per-wave LDS.
// ---------------------------------------------------------------------------
template<int NSPLIT>
__global__ __launch_bounds__(256, 2) void flash_kernel(
    const _Float16* __restrict__ QT, const _Float16* __restrict__ KF,
    const _Float16* __restrict__ Vg,
    _Float16* __restrict__ O_part, float* __restrict__ m_part, float* __restrict__ l_part)
{
    constexpr int KPS    = NSEQ / NSPLIT;
    constexpr int KITERS = KPS / KTILE;

    __shared__ __align__(16) _Float16 V_s[CDIM * 72];     // [c][key], 36 dw stride
    __shared__ __align__(16) _Float16 P_s[4 * 32 * 72];   // per-wave [q][key]
    __shared__ float alpha_s[4][32];

    const int tid  = threadIdx.x;
    const int lane = tid & 63, wave = tid >> 6;
    const int L31  = lane & 31, hi = lane >> 5;
    const int qtile = blockIdx.x, split = blockIdx.y, b = blockIdx.z;
    const int q0 = qtile * 128 + wave * 32;

    // resident Q B-fragments: B[k=c][col=q=L31]
    h8_t qf[12];
    const _Float16* qbase = QT + ((size_t)b * NSEQ + q0 + L31) * CDIM + hi * 8;
    #pragma unroll
    for (int t = 0; t < 12; t++) qf[t] = *(const h8_t*)(qbase + t * 16);

    f16v acc[6];
    #pragma unroll
    for (int s = 0; s < 6; s++)
        #pragma unroll
        for (int r = 0; r < 16; r++) acc[s][r] = 0.f;
    float m_run = -__builtin_inff();
    float l_run = 0.f;

    // fragment-ordered K base for this (b, split), lane offset folded in
    const _Float16* kfb = KF + (size_t)b * (288 * 6144)
                        + (size_t)(split * (KPS / 32)) * 6144 + (size_t)lane * 8;
    const _Float16* vsrc = Vg + (size_t)b * CDIM * NSEQ + split * KPS;

    // V staging map (loop-invariant)
    const _Float16* vgl[6];
    _Float16*       vds[6];
    #pragma unroll
    for (int r = 0; r < 6; r++) {
        int i = r * 256 + tid;
        int c = i >> 3, seg = i & 7;
        vgl[r] = vsrc + (size_t)c * NSEQ + seg * 8;
        vds[r] = V_s + c * 72 + seg * 8;
    }
    h8_t vreg[6];
    #pragma unroll
    for (int r = 0; r < 6; r++) vreg[r] = *(const h8_t*)(vgl[r]);

    for (int kt = 0; kt < KITERS; kt++) {
        // issue first two t-steps of K frags NOW — in flight across staging
        const _Float16* kf0 = kfb + (size_t)(kt * 2) * 6144;
        const _Float16* kf1 = kf0 + 6144;
        h8_t cur0 = *(const h8_t*)(kf0);
        h8_t cur1 = *(const h8_t*)(kf1);
        h8_t nxt0 = *(const h8_t*)(kf0 + 512);
        h8_t nxt1 = *(const h8_t*)(kf1 + 512);

        __syncthreads();                    // prev iter's V_s reads done
        #pragma unroll
        for (int r = 0; r < 6; r++) *(h8_t*)(vds[r]) = vreg[r];
        __syncthreads();                    // V tile ready
        if (kt + 1 < KITERS) {              // V loads in flight through compute
            #pragma unroll
            for (int r = 0; r < 6; r++)
                vreg[r] = *(const h8_t*)(vgl[r] + (kt + 1) * KTILE);
        }

        // ---- S^T = K_tile * Q, K frags from global, 2-step window ----
        f16v st[2];
        #pragma unroll
        for (int s = 0; s < 2; s++)
            #pragma unroll
            for (int r = 0; r < 16; r++) st[s][r] = 0.f;
        #pragma unroll
        for (int t = 0; t < 12; t++) {
            h8_t pf0 = nxt0, pf1 = nxt1;
            if (t + 2 < 12) {
                pf0 = *(const h8_t*)(kf0 + (t + 2) * 512);
                pf1 = *(const h8_t*)(kf1 + (t + 2) * 512);
            }
            st[0] = __builtin_amdgcn_mfma_f32_32x32x16_f16(cur0, qf[t], st[0], 0, 0, 0);
            st[1] = __builtin_amdgcn_mfma_f32_32x32x16_f16(cur1, qf[t], st[1], 0, 0, 0);
            cur0 = nxt0; cur1 = nxt1; nxt0 = pf0; nxt1 = pf1;
        }

        // ---- online softmax (log2 domain), balanced trees ----
        float v[32];
        #pragma unroll
        for (int r = 0; r < 16; r++) { v[r] = st[0][r]; v[16 + r] = st[1][r]; }
        float mv[32];
        #pragma unroll
        for (int r = 0; r < 32; r++) mv[r] = v[r];
        #pragma unroll
        for (int w = 16; w >= 1; w >>= 1)
            #pragma unroll
            for (int i = 0; i < w; i++) mv[i] = fmaxf(mv[i], mv[i + w]);
        float mx = fmaxf(mv[0], __shfl_xor(mv[0], 32));
        float m_new = fmaxf(m_run, mx);

        float p[32];
        #pragma unroll
        for (int r = 0; r < 32; r++) p[r] = __builtin_exp2f(v[r] - m_new);
        float sv[32];
        #pragma unroll
        for (int r = 0; r < 32; r++) sv[r] = p[r];
        #pragma unroll
        for (int w = 16; w >= 1; w >>= 1)
            #pragma unroll
            for (int i = 0; i < w; i++) sv[i] += sv[i + w];
        float psum = sv[0];

        if (__any(m_new > m_run)) {
            float alpha = __builtin_exp2f(m_run - m_new);   // -inf -> 0 first iter
            l_run = l_run * alpha + psum;
            if (lane < 32) alpha_s[wave][lane] = alpha;
            __asm__ volatile("" ::: "memory");
            f4_t a4[4];
            #pragma unroll
            for (int g = 0; g < 4; g++)
                a4[g] = *(const f4_t*)&alpha_s[wave][8 * g + 4 * hi];
            #pragma unroll
            for (int cs = 0; cs < 6; cs++)
                #pragma unroll
                for (int r = 0; r < 16; r++) acc[cs][r] *= a4[r >> 2][r & 3];
        } else {
            l_run += psum;
        }
        m_run = m_new;

        // P -> LDS, [q][key] (key = s*32 + 8g + 4hi + r)
        _Float16* prow = P_s + wave * 32 * 72 + L31 * 72;
        #pragma unroll
        for (int s = 0; s < 2; s++)
            #pragma unroll
            for (int g = 0; g < 4; g++) {
                h4_t h = {(_Float16)p[s*16+4*g+0], (_Float16)p[s*16+4*g+1],
                          (_Float16)p[s*16+4*g+2], (_Float16)p[s*16+4*g+3]};
                *(h4_t*)(prow + s * 32 + 8 * g + 4 * hi) = h;
            }
        __asm__ volatile("" ::: "memory");

        // ---- PV: O^T[q][c] += P[q][key] * V[c][key] ----
        #pragma unroll
        for (int ks = 0; ks < 4; ks++) {
            h8_t pa = *(const h8_t*)(prow + ks * 16 + hi * 8);
            #pragma unroll
            for (int cs = 0; cs < 6; cs++) {
                h8_t vb = *(const h8_t*)(V_s + (cs * 32 + L31) * 72 + ks * 16 + hi * 8);
                acc[cs] = __builtin_amdgcn_mfma_f32_32x32x16_f16(pa, vb, acc[cs], 0, 0, 0);
            }
        }
    }

    // epilogue: unnormalized partials
    float l_tot = l_run + __shfl_xor(l_run, 32);
    const size_t pbase = (size_t)(b * NSPLIT + split) * NSEQ + q0;
    if (lane < 32) {
        m_part[pbase + lane] = m_run;
        l_part[pbase + lane] = l_tot;
    }
    _Float16* obase = O_part + pbase * CDIM;
    #pragma unroll
    for (int cs = 0; cs < 6; cs++)
        #pragma unroll
        for (int r = 0; r < 16; r++) {
            int q = (r & 3) + 8 * (r >> 2) + 4 * hi;
            obase[(size_t)q * CDIM + cs * 32 + L31] = (_Float16)acc[cs][r];
        }
}

// ---------------------------------------------------------------------------
// Kernel 3: merge NS splits, normalize (log2 domain), transpose to out[b][c][n]
// ---------------------------------------------------------------------------
template<int NS>
__global__ __launch_bounds__(256) void combine_kernel(
    const _Float16* __restrict__ O_part, const float* __restrict__ m_part,
    const float* __restrict__ l_part, float* __restrict__ out)
{
    __shared__ float Cs[CDIM][65];
    __shared__ float winv[NS][64];
    const int tid = threadIdx.x;
    const int b  = blockIdx.y;
    const int n0 = blockIdx.x * 64;

    if (tid < 64) {
        int n = n0 + tid;
        float mm[NS], ll[NS], ms = -__builtin_inff();
        #pragma unroll
        for (int s = 0; s < NS; s++) {
            mm[s] = m_part[(b * NS + s) * NSEQ + n];
            ll[s] = l_part[(b * NS + s) * NSEQ + n];
            ms = fmaxf(ms, mm[s]);
        }
        float denom = 0.f;
        #pragma unroll
        for (int s = 0; s < NS; s++) {
            float w = __builtin_exp2f(mm[s] - ms);
            mm[s] = w;
            denom += w * ll[s];
        }
        #pragma unroll
        for (int s = 0; s < NS; s++) winv[s][tid] = mm[s] / denom;
    }
    __syncthreads();

    for (int i = tid; i < 64 * 48; i += 256) {
        int nl = i / 48, c4 = i % 48;
        float v0 = 0.f, v1 = 0.f, v2 = 0.f, v3 = 0.f;
        #pragma unroll
        for (int s = 0; s < NS; s++) {
            h4_t op = *(const h4_t*)(O_part +
                ((size_t)(b * NS + s) * NSEQ + n0 + nl) * CDIM + c4 * 4);
            float w = winv[s][nl];
            v0 += w * (float)op[0];
            v1 += w * (float)op[1];
            v2 += w * (float)op[2];
            v3 += w * (float)op[3];
        }
        Cs[c4 * 4 + 0][nl] = v0;
        Cs[c4 * 4 + 1][nl] = v1;
        Cs[c4 * 4 + 2][nl] = v2;
        Cs[c4 * 4 + 3][nl] = v3;
    }
    __syncthreads();
    for (int i = tid; i < CDIM * 64; i += 256) {
        int nl = i & 63, c = i >> 6;
        out[((size_t)b * CDIM + c) * NSEQ + n0 + nl] = Cs[c][nl];
    }
}

// ---------------------------------------------------------------------------
extern "C" void kernel_launch(void* const* d_in, const int* in_sizes, int n_in,
                              void* d_out, int out_size, void* d_ws, size_t ws_size,
                              hipStream_t stream)
{
    const float* x  = (const float*)d_in[0];
    const float* Wq = (const float*)d_in[1];
    const float* bq = (const float*)d_in[2];
    const float* Wk = (const float*)d_in[3];
    const float* bk = (const float*)d_in[4];
    const float* Wv = (const float*)d_in[5];
    const float* bv = (const float*)d_in[6];
    float* out = (float*)d_out;

    // workspace layout
    char* ws = (char*)d_ws;
    _Float16* QT = (_Float16*)(ws);                    // 7,077,888 B
    _Float16* KF = (_Float16*)(ws + 7077888);          // fragment-ordered K
    _Float16* Vg = (_Float16*)(ws + 14155776);
    char* tail = ws + 21233664;
    _Float16* Wh = (_Float16*)tail;                    // 221,184 B, aliases O_part
    _Float16* O_part = (_Float16*)tail;                // NS * 7,077,888 B (f16)

    wconv_kernel<<<108, 256, 0, stream>>>(Wq, Wk, Wv, Wh);
    proj_kernel<<<864, 256, 0, stream>>>(x, Wh, bq, bk, bv, QT, KF, Vg);

    const size_t need8 = 21233664ull + 8 * 7077888ull + 2 * 589824ull;  // 79,036,416
    const size_t need4 = 21233664ull + 4 * 7077888ull + 2 * 294912ull;  // 50,135,040
    if (ws_size >= need8) {
        float* m_part = (float*)(tail + 8 * 7077888ull);
        float* l_part = (float*)(tail + 8 * 7077888ull + 589824ull);
        flash_kernel<8><<<dim3(72, 8, 2), 256, 0, stream>>>(QT, KF, Vg, O_part, m_part, l_part);
        combine_kernel<8><<<dim3(144, 2), 256, 0, stream>>>(O_part, m_part, l_part, out);
    } else if (ws_size >= need4) {
        float* m_part = (float*)(tail + 4 * 7077888ull);
        float* l_part = (float*)(tail + 4 * 7077888ull + 294912ull);
        flash_kernel<4><<<dim3(72, 4, 2), 256, 0, stream>>>(QT, KF, Vg, O_part, m_part, l_part);
        combine_kernel<4><<<dim3(144, 2), 256, 0, stream>>>(O_part, m_part, l_part, out);
    } else {
        float* m_part = (float*)(tail + 2 * 7077888ull);
        float* l_part = (float*)(tail + 2 * 7077888ull + 147456ull);
        flash_kernel<2><<<dim3(72, 2, 2), 256, 0, stream>>>(QT, KF, Vg, O_part, m_part, l_part);
        combine_kernel<2><<<dim3(144, 2), 256, 0, stream>>>(O_part, m_part, l_part, out);
    }
}